// Round 4
// baseline (331.168 us; speedup 1.0000x reference)
//
#include <hip/hip_runtime.h>
#include <math.h>

#define S_LEN 2048
#define D_DIM 1024
#define NB    4

typedef __bf16 bf16_t;
typedef __bf16 bf16x8 __attribute__((ext_vector_type(8)));
typedef float  f32x4  __attribute__((ext_vector_type(4)));
typedef unsigned int   u32;
typedef unsigned short u16;
typedef unsigned int   u32x4 __attribute__((ext_vector_type(4)));

#define BM 128
#define BN 128
#define BK 64    // 64 bf16 = 128 B per row
#define BM2 256
#define BN2 256

__device__ __forceinline__ u16 f2b_bits(float x) {
    bf16_t h = (bf16_t)x;
    return *(u16*)&h;
}

// async global->LDS, 16B per lane; lds ptr must be wave-uniform base (HW adds lane*16)
__device__ __forceinline__ void async16(const void* g, void* l) {
    __builtin_amdgcn_global_load_lds(
        (__attribute__((address_space(1))) const void*)g,
        (__attribute__((address_space(3))) void*)l, 16, 0, 0);
}

// raw barrier: no compiler-inserted vmcnt(0)/lgkmcnt(0) drain; memory clobber
// pins all memory ops on their side of the barrier.
#define BAR_RAW() asm volatile("s_barrier" ::: "memory")

// ============================================================================
// 256x256 4-phase GEMM core (T3+T4+T5): C = A[M,K] x Bt[N,K]^T + bias, bf16 in.
// 512 thr / 8 waves (2Mx4N), per-wave 128x64 out, BK=64, 128 KB LDS dbuf.
// Per K-tile J: 4 phases, each {ds_read subtile | stage half-tile | barrier |
// setprio(1) 16 MFMA setprio(0) | barrier}; counted vmcnt(4) once per K-tile
// (A(J+2) staged at ph3 = the 4 allowed-outstanding loads; A(J+1)/B(J+1)
// proven landed). XOR bank swizzle identical to the verified 128 core.
// ============================================================================
__global__ __launch_bounds__(512, 2) void k_gemm_proj8(
    const bf16_t* __restrict__ Xb, const bf16_t* __restrict__ Wt,
    const float* __restrict__ bq, const float* __restrict__ bk,
    const float* __restrict__ bv, bf16_t* __restrict__ Pr)
{
    __shared__ __attribute__((aligned(16))) bf16_t lA[2][BM2 * BK];   // 2 x 32 KB
    __shared__ __attribute__((aligned(16))) bf16_t lB[2][BN2 * BK];   // 2 x 32 KB
    const int z = blockIdx.z;
    const bf16_t* A  = Xb + (long)z * ((long)NB * S_LEN * D_DIM);
    const bf16_t* Bt = Wt + (long)z * D_DIM * D_DIM;
    bf16_t* C        = Pr + (long)z * ((long)NB * S_LEN * D_DIM);
    const float* bias = (z == 0) ? bq : ((z == 1) ? bk : bv);
    const int m0 = blockIdx.x * BM2, n0 = blockIdx.y * BN2;
    const int KT = D_DIM / BK;           // 16

    const int t = threadIdx.x;
    const int w = t >> 6, lane = t & 63;
    const int wr = w >> 2, wc = w & 3;   // 2x4 wave grid; wave tile 128x64
    const int srow = lane >> 3, slot = lane & 7;
    const int kb_src = (slot ^ srow) * 8;        // pre-swizzled global column
    const int fr = lane & 15, fq = lane >> 4;
    const int fofh0 = ((fq       ^ (fr & 7)) * 8);
    const int fofh1 = (((4 + fq) ^ (fr & 7)) * 8);
    const int rbA = (wr * 128 + fr) * BK;
    const int rbB = (wc * 64  + fr) * BK;

    // staging: each wave covers rows [w*8, w*8+8) of every 64-row round
    const bf16_t* gA = A  + (long)(m0 + w * 8 + srow) * D_DIM + kb_src;
    const bf16_t* gB = Bt + (long)(n0 + w * 8 + srow) * D_DIM + kb_src;
    const int ldsw = (w * 8) * BK;

    f32x4 acc[8][4];
#pragma unroll
    for (int mt = 0; mt < 8; ++mt)
#pragma unroll
        for (int nt = 0; nt < 4; ++nt)
            acc[mt][nt] = f32x4{0.f, 0.f, 0.f, 0.f};

    // prologue: stage A(0), B(0), A(1); keep A(1) (4 loads) in flight
    {
        const long kc1 = BK;
        async16(gA,                     &lA[0][0   * BK + ldsw]);
        async16(gA + (long)64  * D_DIM, &lA[0][64  * BK + ldsw]);
        async16(gA + (long)128 * D_DIM, &lA[0][128 * BK + ldsw]);
        async16(gA + (long)192 * D_DIM, &lA[0][192 * BK + ldsw]);
        async16(gB,                     &lB[0][0   * BK + ldsw]);
        async16(gB + (long)64  * D_DIM, &lB[0][64  * BK + ldsw]);
        async16(gB + (long)128 * D_DIM, &lB[0][128 * BK + ldsw]);
        async16(gB + (long)192 * D_DIM, &lB[0][192 * BK + ldsw]);
        async16(gA + kc1,                     &lA[1][0   * BK + ldsw]);
        async16(gA + kc1 + (long)64  * D_DIM, &lA[1][64  * BK + ldsw]);
        async16(gA + kc1 + (long)128 * D_DIM, &lA[1][128 * BK + ldsw]);
        async16(gA + kc1 + (long)192 * D_DIM, &lA[1][192 * BK + ldsw]);
        asm volatile("s_waitcnt vmcnt(4)" ::: "memory");
        BAR_RAW();
    }

#pragma unroll 1
    for (int J = 0; J < KT; ++J) {
        const int pb = J & 1;
        const bf16_t* lab = lA[pb];
        const bf16_t* lbb = lB[pb];
        bf16_t* lbn = lB[pb ^ 1];
        bf16_t* laS = lA[pb];              // A(J+2) reuses this buffer
        const long kc1 = (long)(J + 1) * BK;
        const long kc2 = (long)(J + 2) * BK;
        bf16x8 af[4][2], b0f[2][2], b1f[2][2];

        // ---- ph0: read af(mh0)+bf0; stage B-half0(J+1); MFMA mh0 x nh0
#pragma unroll
        for (int mt = 0; mt < 4; ++mt) {
            af[mt][0] = *(const bf16x8*)(lab + rbA + mt * 16 * BK + fofh0);
            af[mt][1] = *(const bf16x8*)(lab + rbA + mt * 16 * BK + fofh1);
        }
#pragma unroll
        for (int nt = 0; nt < 2; ++nt) {
            b0f[nt][0] = *(const bf16x8*)(lbb + rbB + nt * 16 * BK + fofh0);
            b0f[nt][1] = *(const bf16x8*)(lbb + rbB + nt * 16 * BK + fofh1);
        }
        if (J + 1 < KT) {
            async16(gB + kc1,                    lbn + 0  * BK + ldsw);
            async16(gB + kc1 + (long)64 * D_DIM, lbn + 64 * BK + ldsw);
        }
        BAR_RAW();
        __builtin_amdgcn_s_setprio(1);
#pragma unroll
        for (int mt = 0; mt < 4; ++mt)
#pragma unroll
            for (int nt = 0; nt < 2; ++nt) {
                acc[mt][nt] = __builtin_amdgcn_mfma_f32_16x16x32_bf16(
                    af[mt][0], b0f[nt][0], acc[mt][nt], 0, 0, 0);
                acc[mt][nt] = __builtin_amdgcn_mfma_f32_16x16x32_bf16(
                    af[mt][1], b0f[nt][1], acc[mt][nt], 0, 0, 0);
            }
        __builtin_amdgcn_s_setprio(0);
        BAR_RAW();

        // ---- ph1: read bf1; stage B-half1(J+1); MFMA mh0 x nh1
#pragma unroll
        for (int nt = 0; nt < 2; ++nt) {
            b1f[nt][0] = *(const bf16x8*)(lbb + rbB + (2 + nt) * 16 * BK + fofh0);
            b1f[nt][1] = *(const bf16x8*)(lbb + rbB + (2 + nt) * 16 * BK + fofh1);
        }
        if (J + 1 < KT) {
            async16(gB + kc1 + (long)128 * D_DIM, lbn + 128 * BK + ldsw);
            async16(gB + kc1 + (long)192 * D_DIM, lbn + 192 * BK + ldsw);
        }
        BAR_RAW();
        __builtin_amdgcn_s_setprio(1);
#pragma unroll
        for (int mt = 0; mt < 4; ++mt)
#pragma unroll
            for (int nt = 0; nt < 2; ++nt) {
                acc[mt][2 + nt] = __builtin_amdgcn_mfma_f32_16x16x32_bf16(
                    af[mt][0], b1f[nt][0], acc[mt][2 + nt], 0, 0, 0);
                acc[mt][2 + nt] = __builtin_amdgcn_mfma_f32_16x16x32_bf16(
                    af[mt][1], b1f[nt][1], acc[mt][2 + nt], 0, 0, 0);
            }
        __builtin_amdgcn_s_setprio(0);
        BAR_RAW();

        // ---- ph2: read af(mh1) (af regs reused; mh0 set dead); MFMA mh1 x nh1
#pragma unroll
        for (int mt = 0; mt < 4; ++mt) {
            af[mt][0] = *(const bf16x8*)(lab + rbA + (64 + mt * 16) * BK + fofh0);
            af[mt][1] = *(const bf16x8*)(lab + rbA + (64 + mt * 16) * BK + fofh1);
        }
        BAR_RAW();
        __builtin_amdgcn_s_setprio(1);
#pragma unroll
        for (int mt = 0; mt < 4; ++mt)
#pragma unroll
            for (int nt = 0; nt < 2; ++nt) {
                acc[4 + mt][2 + nt] = __builtin_amdgcn_mfma_f32_16x16x32_bf16(
                    af[mt][0], b1f[nt][0], acc[4 + mt][2 + nt], 0, 0, 0);
                acc[4 + mt][2 + nt] = __builtin_amdgcn_mfma_f32_16x16x32_bf16(
                    af[mt][1], b1f[nt][1], acc[4 + mt][2 + nt], 0, 0, 0);
            }
        __builtin_amdgcn_s_setprio(0);
        BAR_RAW();

        // ---- ph3: stage A(J+2) (region free since ph2-end barrier);
        //           MFMA mh1 x nh0; counted vmcnt before phase-end barrier
        if (J + 2 < KT) {
            async16(gA + kc2,                     laS + 0   * BK + ldsw);
            async16(gA + kc2 + (long)64  * D_DIM, laS + 64  * BK + ldsw);
            async16(gA + kc2 + (long)128 * D_DIM, laS + 128 * BK + ldsw);
            async16(gA + kc2 + (long)192 * D_DIM, laS + 192 * BK + ldsw);
        }
        BAR_RAW();
        __builtin_amdgcn_s_setprio(1);
#pragma unroll
        for (int mt = 0; mt < 4; ++mt)
#pragma unroll
            for (int nt = 0; nt < 2; ++nt) {
                acc[4 + mt][nt] = __builtin_amdgcn_mfma_f32_16x16x32_bf16(
                    af[mt][0], b0f[nt][0], acc[4 + mt][nt], 0, 0, 0);
                acc[4 + mt][nt] = __builtin_amdgcn_mfma_f32_16x16x32_bf16(
                    af[mt][1], b0f[nt][1], acc[4 + mt][nt], 0, 0, 0);
            }
        __builtin_amdgcn_s_setprio(0);
        // allow only A(J+2)'s 4 loads outstanding -> A(J+1)+B(J+1) landed
        if (J + 2 < KT)      asm volatile("s_waitcnt vmcnt(4)" ::: "memory");
        else if (J + 1 < KT) asm volatile("s_waitcnt vmcnt(0)" ::: "memory");
        BAR_RAW();
    }

    // epilogue: C = acc + bias
    const int r0 = m0 + wr * 128 + fq * 4;
    const int c0 = n0 + wc * 64 + fr;
#pragma unroll
    for (int mt = 0; mt < 8; ++mt)
#pragma unroll
        for (int nt = 0; nt < 4; ++nt) {
            const int col = c0 + nt * 16;
            const float bb = bias[col];
#pragma unroll
            for (int r = 0; r < 4; ++r) {
                const int row = r0 + mt * 16 + r;
                C[(long)row * D_DIM + col] = (bf16_t)(acc[mt][nt][r] + bb);
            }
        }
}

// Double-buffered 128x128 core with counted vmcnt (used by scores/pv).
__device__ __forceinline__ void gemm_bt_dbuf(
    const bf16_t* __restrict__ A, const bf16_t* __restrict__ Bt,
    int lda, int ldb, int m0, int n0, int kTiles, f32x4 (&acc)[4][4])
{
    __shared__ __attribute__((aligned(16))) bf16_t lA[2][BM * BK];   // 32 KB
    __shared__ __attribute__((aligned(16))) bf16_t lB[2][BN * BK];   // 32 KB
    const int t    = threadIdx.x;
    const int w    = t >> 6;
    const int lane = t & 63;
    const int wr   = w >> 1, wc = w & 1;
    const int srow   = lane >> 3;
    const int kb_src = ((lane & 7) ^ (lane >> 3)) * 8;
    const int fr = lane & 15, fq = lane >> 4;
    const int fof0 = (((0 * 4 + fq) ^ (fr & 7)) * 8);
    const int fof1 = (((1 * 4 + fq) ^ (fr & 7)) * 8);
    const int aO0 = (wr * 64 + fr) * BK + fof0;
    const int aO1 = (wr * 64 + fr) * BK + fof1;
    const int bO0 = (wc * 64 + fr) * BK + fof0;
    const int bO1 = (wc * 64 + fr) * BK + fof1;
    const int sOf = (w * 32) * BK;
    const bf16_t* gA = A  + (long)(m0 + w * 32 + srow) * lda + kb_src;
    const bf16_t* gB = Bt + (long)(n0 + w * 32 + srow) * ldb + kb_src;

#pragma unroll
    for (int mt = 0; mt < 4; ++mt)
#pragma unroll
        for (int nt = 0; nt < 4; ++nt)
            acc[mt][nt] = f32x4{0.f, 0.f, 0.f, 0.f};

#pragma unroll
    for (int i = 0; i < 4; ++i) {
        async16(gA + (long)(i * 8) * lda, &lA[0][sOf + i * 8 * BK]);
        async16(gB + (long)(i * 8) * ldb, &lB[0][sOf + i * 8 * BK]);
    }

    for (int kt = 0; kt < kTiles; ++kt) {
        const int cur = kt & 1, nxt = cur ^ 1;
        if (kt + 1 < kTiles) {
            const long k1 = (long)(kt + 1) * BK;
#pragma unroll
            for (int i = 0; i < 4; ++i) {
                async16(gA + k1 + (long)(i * 8) * lda, &lA[nxt][sOf + i * 8 * BK]);
                async16(gB + k1 + (long)(i * 8) * ldb, &lB[nxt][sOf + i * 8 * BK]);
            }
            asm volatile("s_waitcnt vmcnt(8)" ::: "memory");
        } else {
            asm volatile("s_waitcnt vmcnt(0)" ::: "memory");
        }
        BAR_RAW();
        const bf16_t* lac = lA[cur];
        const bf16_t* lbc = lB[cur];
#pragma unroll
        for (int h = 0; h < 2; ++h) {
            const bf16_t* pa = lac + (h ? aO1 : aO0);
            const bf16_t* pb = lbc + (h ? bO1 : bO0);
            bf16x8 af[4], bfv[4];
#pragma unroll
            for (int mt = 0; mt < 4; ++mt)
                af[mt] = *(const bf16x8*)(pa + mt * 16 * BK);
#pragma unroll
            for (int nt = 0; nt < 4; ++nt)
                bfv[nt] = *(const bf16x8*)(pb + nt * 16 * BK);
#pragma unroll
            for (int mt = 0; mt < 4; ++mt)
#pragma unroll
                for (int nt = 0; nt < 4; ++nt)
                    acc[mt][nt] = __builtin_amdgcn_mfma_f32_16x16x32_bf16(
                        af[mt], bfv[nt], acc[mt][nt], 0, 0, 0);
        }
        BAR_RAW();
    }
}

// q/k/v fp32 -> bf16; one float4 per thread (dense coalescing), 8B store
__global__ __launch_bounds__(256) void k_f2b(
    const float* __restrict__ q, const float* __restrict__ k,
    const float* __restrict__ v, bf16_t* __restrict__ Xb)
{
    const int z = blockIdx.z;
    const float* src = (z == 0) ? q : ((z == 1) ? k : v);
    bf16_t* dst = Xb + (long)z * ((long)NB * S_LEN * D_DIM);
    const long i = (long)blockIdx.x * blockDim.x + threadIdx.x;
    float4 a = ((const float4*)src)[i];
    u32 lo = (u32)f2b_bits(a.x) | ((u32)f2b_bits(a.y) << 16);
    u32 hi = (u32)f2b_bits(a.z) | ((u32)f2b_bits(a.w) << 16);
    ((uint2*)(dst))[i] = make_uint2(lo, hi);
}

// W [K=1024,N=1024] fp32 -> Wt [N,K] bf16. 64x64 tiles, vectorized I/O.
__global__ __launch_bounds__(256) void k_tw(
    const float* __restrict__ Wq, const float* __restrict__ Wk,
    const float* __restrict__ Wv, bf16_t* __restrict__ Wt)
{
    __shared__ u32 tile[64][33];
    const int z = blockIdx.z;
    const float* W = (z == 0) ? Wq : ((z == 1) ? Wk : Wv);
    bf16_t* T = Wt + (long)z * D_DIM * D_DIM;
    const int t = threadIdx.x;
    const int k0 = blockIdx.x * 64, n0 = blockIdx.y * 64;
#pragma unroll
    for (int rr = 0; rr < 4; ++rr) {
        const int kr = (t >> 4) + rr * 16;
        const int nq = (t & 15) * 4;
        float4 f = *(const float4*)(W + (long)(k0 + kr) * D_DIM + n0 + nq);
        tile[kr][(nq >> 1)]     = (u32)f2b_bits(f.x) | ((u32)f2b_bits(f.y) << 16);
        tile[kr][(nq >> 1) + 1] = (u32)f2b_bits(f.z) | ((u32)f2b_bits(f.w) << 16);
    }
    __syncthreads();
#pragma unroll
    for (int rr = 0; rr < 2; ++rr) {
        const int nr = (t >> 3) + rr * 32;
        const int j0 = (t & 7) * 4;
        u32x4 o;
#pragma unroll
        for (int jj = 0; jj < 4; ++jj) {
            const int j = j0 + jj;
            const u32 ua = tile[2 * j][nr >> 1];
            const u32 ub = tile[2 * j + 1][nr >> 1];
            const u32 lo = (nr & 1) ? (ua >> 16) : (ua & 0xffffu);
            const u32 hi = (nr & 1) ? (ub >> 16) : (ub & 0xffffu);
            o[jj] = lo | (hi << 16);
        }
        *(u32x4*)(T + (long)(n0 + nr) * D_DIM + k0 + 2 * j0) = o;
    }
}

// WV [S,D] bf16 -> WVt [D,S] bf16 per batch. 64x64 tiles, vectorized I/O.
__global__ __launch_bounds__(256) void k_tv(
    const bf16_t* __restrict__ PrV, bf16_t* __restrict__ WVt)
{
    __shared__ u32 tile[64][33];
    const int b = blockIdx.z;
    const bf16_t* src = PrV + (long)b * S_LEN * D_DIM;
    bf16_t* dst = WVt + (long)b * D_DIM * S_LEN;
    const int t = threadIdx.x;
    const int d0 = blockIdx.x * 64, s0 = blockIdx.y * 64;
#pragma unroll
    for (int rr = 0; rr < 2; ++rr) {
        const int sr = (t >> 3) + rr * 32;
        const int dp0 = (t & 7) * 4;
        u32x4 u = *(const u32x4*)(src + (long)(s0 + sr) * D_DIM + d0 + 2 * dp0);
#pragma unroll
        for (int q = 0; q < 4; ++q) tile[sr][dp0 + q] = u[q];
    }
    __syncthreads();
#pragma unroll
    for (int rr = 0; rr < 2; ++rr) {
        const int dr = (t >> 3) + rr * 32;
        const int j0 = (t & 7) * 4;
        u32x4 o;
#pragma unroll
        for (int jj = 0; jj < 4; ++jj) {
            const int j = j0 + jj;
            const u32 ua = tile[2 * j][dr >> 1];
            const u32 ub = tile[2 * j + 1][dr >> 1];
            const u32 lo = (dr & 1) ? (ua >> 16) : (ua & 0xffffu);
            const u32 hi = (dr & 1) ? (ub >> 16) : (ub & 0xffffu);
            o[jj] = lo | (hi << 16);
        }
        *(u32x4*)(dst + (long)(d0 + dr) * S_LEN + s0 + 2 * j0) = o;
    }
}

// scores = (WQ @ WK^T) / 32, causal, triangular block enumeration.
__global__ __launch_bounds__(256) void k_gemm_scores(
    const bf16_t* __restrict__ PrQ, const bf16_t* __restrict__ PrK,
    bf16_t* __restrict__ SC)
{
    const int u = blockIdx.x, b = blockIdx.z;
    int ti = (int)((sqrtf(8.0f * (float)u + 1.0f) - 1.0f) * 0.5f);
    while ((ti + 1) * (ti + 2) / 2 <= u) ++ti;
    while (ti * (ti + 1) / 2 > u) --ti;
    const int tj = u - ti * (ti + 1) / 2;
    const bf16_t* A  = PrQ + (long)b * S_LEN * D_DIM;
    const bf16_t* Bt = PrK + (long)b * S_LEN * D_DIM;
    bf16_t* C        = SC  + (long)b * S_LEN * S_LEN;
    const int m0 = ti * BM, n0 = tj * BN;
    f32x4 acc[4][4];
    gemm_bt_dbuf(A, Bt, D_DIM, D_DIM, m0, n0, D_DIM / BK, acc);
    const int lane = threadIdx.x & 63, w = threadIdx.x >> 6;
    const int wr = w >> 1, wc = w & 1;
    const int r0 = m0 + wr * 64 + (lane >> 4) * 4;
    const int c0 = n0 + wc * 64 + (lane & 15);
#pragma unroll
    for (int mt = 0; mt < 4; ++mt)
#pragma unroll
        for (int nt = 0; nt < 4; ++nt) {
            const int col = c0 + nt * 16;
#pragma unroll
            for (int r = 0; r < 4; ++r) {
                const int row = r0 + mt * 16 + r;
                C[(long)row * S_LEN + col] = (bf16_t)(acc[mt][nt][r] * 0.03125f);
            }
        }
}

// causal softmax, wave-per-row, register-resident, shuffle reductions.
__global__ __launch_bounds__(256) void k_softmax(bf16_t* __restrict__ SC)
{
    const int w = threadIdx.x >> 6, lane = threadIdx.x & 63;
    const int i = blockIdx.x * 4 + w;
    const int b = blockIdx.y;
    bf16_t* row = SC + ((long)b * S_LEN + i) * S_LEN;
    const int n    = i + 1;
    const int jend = ((i >> 7) + 1) << 7;
    const int nch  = (jend + 511) >> 9;
    float x[4][8];
    float mx = -1e30f;
#pragma unroll
    for (int c = 0; c < 4; ++c) {
        if (c < nch) {
            bf16x8 vv = *(const bf16x8*)(row + c * 512 + lane * 8);
#pragma unroll
            for (int e = 0; e < 8; ++e) {
                const int j = c * 512 + lane * 8 + e;
                const float f = (j < n) ? (float)vv[e] : -1e30f;
                x[c][e] = f;
                mx = fmaxf(mx, f);
            }
        }
    }
#pragma unroll
    for (int d = 1; d < 64; d <<= 1) mx = fmaxf(mx, __shfl_xor(mx, d, 64));
    float sm = 0.f;
#pragma unroll
    for (int c = 0; c < 4; ++c) {
        if (c < nch) {
#pragma unroll
            for (int e = 0; e < 8; ++e) {
                const int j = c * 512 + lane * 8 + e;
                float p = (j < n) ? __expf(x[c][e] - mx) : 0.f;
                x[c][e] = p;
                sm += p;
            }
        }
    }
#pragma unroll
    for (int d = 1; d < 64; d <<= 1) sm += __shfl_xor(sm, d, 64);
    const float inv = 1.0f / sm;
#pragma unroll
    for (int c = 0; c < 4; ++c) {
        if (c < nch) {
            bf16x8 o;
#pragma unroll
            for (int e = 0; e < 8; ++e) o[e] = (bf16_t)(x[c][e] * inv);
            *(bf16x8*)(row + c * 512 + lane * 8) = o;
        }
    }
}

// out = P @ WVt^T, fp32 out; K-loop truncated at diagonal tile. Heavy-first.
__global__ __launch_bounds__(256) void k_gemm_pv(
    const bf16_t* __restrict__ SC, const bf16_t* __restrict__ WVt,
    float* __restrict__ Out)
{
    const int ti = (S_LEN / BM - 1) - blockIdx.y, b = blockIdx.z;
    const bf16_t* A  = SC  + (long)b * S_LEN * S_LEN;
    const bf16_t* Bt = WVt + (long)b * D_DIM * S_LEN;
    float* C         = Out + (long)b * S_LEN * D_DIM;
    const int m0 = ti * BM, n0 = blockIdx.x * BN;
    f32x4 acc[4][4];
    gemm_bt_dbuf(A, Bt, S_LEN, S_LEN, m0, n0, (ti + 1) * (BM / BK), acc);
    const int lane = threadIdx.x & 63, w = threadIdx.x >> 6;
    const int wr = w >> 1, wc = w & 1;
    const int r0 = m0 + wr * 64 + (lane >> 4) * 4;
    const int c0 = n0 + wc * 64 + (lane & 15);
#pragma unroll
    for (int mt = 0; mt < 4; ++mt)
#pragma unroll
        for (int nt = 0; nt < 4; ++nt) {
            const int col = c0 + nt * 16;
#pragma unroll
            for (int r = 0; r < 4; ++r) {
                const int row = r0 + mt * 16 + r;
                C[(long)row * D_DIM + col] = acc[mt][nt][r];
            }
        }
}

extern "C" void kernel_launch(void* const* d_in, const int* in_sizes, int n_in,
                              void* d_out, int out_size, void* d_ws, size_t ws_size,
                              hipStream_t stream)
{
    (void)in_sizes; (void)n_in; (void)out_size; (void)ws_size;
    const float* q  = (const float*)d_in[0];
    const float* k  = (const float*)d_in[1];
    const float* v  = (const float*)d_in[2];
    // d_in[3] = mask: causal triu(1) — applied analytically
    const float* Wq = (const float*)d_in[4];
    const float* bq = (const float*)d_in[5];
    const float* Wk = (const float*)d_in[6];
    const float* bk = (const float*)d_in[7];
    const float* Wv = (const float*)d_in[8];
    const float* bv = (const float*)d_in[9];
    float* out = (float*)d_out;

    // ws layout (bf16 elems): Wt[3*D*D] | Xb[3*B*S*D] (reused as SC[B*S*S]) | Pr[3*B*S*D] | WVt[B*D*S]
    bf16_t* ws = (bf16_t*)d_ws;
    const long nW = (long)D_DIM * D_DIM;           // 1,048,576
    const long nX = (long)NB * S_LEN * D_DIM;      // 8,388,608
    bf16_t* Wt  = ws;
    bf16_t* Xb  = Wt + 3 * nW;
    bf16_t* SC  = Xb;              // aliases Xb: Xb dead after projections
    bf16_t* Pr  = Xb + 3 * nX;
    bf16_t* WVt = Pr + 3 * nX;
    bf16_t* PrQ = Pr;
    bf16_t* PrK = Pr + nX;
    bf16_t* PrV = Pr + 2 * nX;

    k_f2b        <<<dim3(8192, 1, 3),   256,        0, stream>>>(q, k, v, Xb);
    k_tw         <<<dim3(16, 16, 3),    256,        0, stream>>>(Wq, Wk, Wv, Wt);
    k_gemm_proj8 <<<dim3(32, 4, 3),     512,        0, stream>>>(Xb, Wt, bq, bk, bv, Pr);
    k_tv         <<<dim3(16, 32, NB),   256,        0, stream>>>(PrV, WVt);
    k_gemm_scores<<<dim3(136, 1, NB),   256,        0, stream>>>(PrQ, PrK, SC);
    k_softmax    <<<dim3(S_LEN / 4, NB),256,        0, stream>>>(SC);
    k_gemm_pv    <<<dim3(8, 16, NB),    256,        0, stream>>>(SC, WVt, out);
}

// Round 5
// 299.166 us; speedup vs baseline: 1.1070x; 1.1070x over previous
//
#include <hip/hip_runtime.h>
#include <math.h>

#define S_LEN 2048
#define D_DIM 1024
#define NB    4

typedef __bf16 bf16_t;
typedef __bf16 bf16x8 __attribute__((ext_vector_type(8)));
typedef float  f32x4  __attribute__((ext_vector_type(4)));
typedef unsigned int   u32;
typedef unsigned short u16;
typedef unsigned int   u32x4 __attribute__((ext_vector_type(4)));

#define BM 128
#define BN 128
#define BK 64   // 64 bf16 = 128 B per row

__device__ __forceinline__ u16 f2b_bits(float x) {
    bf16_t h = (bf16_t)x;
    return *(u16*)&h;
}

// async global->LDS, 16B per lane; lds ptr must be wave-uniform base (HW adds lane*16)
__device__ __forceinline__ void async16(const void* g, void* l) {
    __builtin_amdgcn_global_load_lds(
        (__attribute__((address_space(1))) const void*)g,
        (__attribute__((address_space(3))) void*)l, 16, 0, 0);
}

// raw barrier: no compiler-inserted vmcnt(0) drain; memory clobber pins ops.
#define BAR_RAW() asm volatile("s_barrier" ::: "memory")

// ============================================================================
// 4-wave 128x128 single-buffer 2-barrier core (proj; throughput regime at
// 1536 blocks -> 5 blocks/CU = 20 waves/CU). Verified: 65 us, MfmaUtil 34%.
// ============================================================================
__device__ __forceinline__ void gemm_bt_core(
    const bf16_t* __restrict__ A, const bf16_t* __restrict__ Bt,
    int lda, int ldb, int m0, int n0, int kTiles, f32x4 (&acc)[4][4])
{
    __shared__ __attribute__((aligned(16))) bf16_t lA[BM * BK];   // 16 KB
    __shared__ __attribute__((aligned(16))) bf16_t lB[BN * BK];   // 16 KB
    const int t    = threadIdx.x;
    const int w    = t >> 6;               // wave 0..3
    const int lane = t & 63;
    const int wr   = w >> 1, wc = w & 1;   // 2x2 wave grid, each wave 64x64
    const int srow   = lane >> 3;
    const int kb_src = ((lane & 7) ^ (lane >> 3)) * 8;
    const int fr = lane & 15, fq = lane >> 4;
    const int fof0 = (((0 * 4 + fq) ^ (fr & 7)) * 8);
    const int fof1 = (((1 * 4 + fq) ^ (fr & 7)) * 8);
    const bf16_t* paB0 = lA + (wr * 64 + fr) * BK + fof0;
    const bf16_t* paB1 = lA + (wr * 64 + fr) * BK + fof1;
    const bf16_t* pbB0 = lB + (wc * 64 + fr) * BK + fof0;
    const bf16_t* pbB1 = lB + (wc * 64 + fr) * BK + fof1;
    bf16_t* ldsA = lA + (w * 32) * BK;
    bf16_t* ldsB = lB + (w * 32) * BK;
    const bf16_t* gA = A  + (long)(m0 + w * 32 + srow) * lda + kb_src;
    const bf16_t* gB = Bt + (long)(n0 + w * 32 + srow) * ldb + kb_src;

#pragma unroll
    for (int mt = 0; mt < 4; ++mt)
#pragma unroll
        for (int nt = 0; nt < 4; ++nt)
            acc[mt][nt] = f32x4{0.f, 0.f, 0.f, 0.f};

    for (int kt = 0; kt < kTiles; ++kt) {
        const long k0 = (long)kt * BK;
#pragma unroll
        for (int i = 0; i < 4; ++i) {
            async16(gA + k0 + (long)(i * 8) * lda, ldsA + i * 8 * BK);
            async16(gB + k0 + (long)(i * 8) * ldb, ldsB + i * 8 * BK);
        }
        asm volatile("s_waitcnt vmcnt(0)" ::: "memory");
        __syncthreads();
#pragma unroll
        for (int h = 0; h < 2; ++h) {
            const bf16_t* pa = h ? paB1 : paB0;
            const bf16_t* pb = h ? pbB1 : pbB0;
            bf16x8 af[4], bfv[4];
#pragma unroll
            for (int mt = 0; mt < 4; ++mt)
                af[mt] = *(const bf16x8*)(pa + mt * 16 * BK);
#pragma unroll
            for (int nt = 0; nt < 4; ++nt)
                bfv[nt] = *(const bf16x8*)(pb + nt * 16 * BK);
#pragma unroll
            for (int mt = 0; mt < 4; ++mt)
#pragma unroll
                for (int nt = 0; nt < 4; ++nt)
                    acc[mt][nt] = __builtin_amdgcn_mfma_f32_16x16x32_bf16(
                        af[mt], bfv[nt], acc[mt][nt], 0, 0, 0);
        }
        __syncthreads();
    }
}

// ============================================================================
// 8-wave 128x128 double-buffer core with counted vmcnt (scores/pv; latency
// regime). 512 thr, wave grid 2Mx4N, 64x32 out/wave, acc[4][2]. 64 KB LDS ->
// 2 blocks/CU = 16 waves/CU (2x the 4-wave core's 8 at these grids), plus
// 1-deep prefetch in flight across barriers. Same XOR swizzle / fragment math
// as the verified 4-wave core (rows mod 8 preserved at every base).
// ============================================================================
__device__ __forceinline__ void gemm_bt_dbuf8(
    const bf16_t* __restrict__ A, const bf16_t* __restrict__ Bt,
    int lda, int ldb, int m0, int n0, int kTiles, f32x4 (&acc)[4][2])
{
    __shared__ __attribute__((aligned(16))) bf16_t lA[2][BM * BK];   // 2x16 KB
    __shared__ __attribute__((aligned(16))) bf16_t lB[2][BN * BK];   // 2x16 KB
    const int t    = threadIdx.x;
    const int w    = t >> 6;               // wave 0..7
    const int lane = t & 63;
    const int wr   = w >> 2, wc = w & 3;   // 2x4 wave grid; wave tile 64x32
    const int srow   = lane >> 3;
    const int kb_src = ((lane & 7) ^ srow) * 8;
    const int fr = lane & 15, fq = lane >> 4;
    const int fof0 = (((0 * 4 + fq) ^ (fr & 7)) * 8);
    const int fof1 = (((1 * 4 + fq) ^ (fr & 7)) * 8);
    const int aO0 = (wr * 64 + fr) * BK + fof0;   // A rows wr*64 + mt*16 + fr
    const int aO1 = (wr * 64 + fr) * BK + fof1;
    const int bO0 = (wc * 32 + fr) * BK + fof0;   // B rows wc*32 + nt*16 + fr
    const int bO1 = (wc * 32 + fr) * BK + fof1;
    const int sOf = (w * 8) * BK;          // wave staging base (8 rows/round)
    const bf16_t* gA = A  + (long)(m0 + w * 8 + srow) * lda + kb_src;
    const bf16_t* gB = Bt + (long)(n0 + w * 8 + srow) * ldb + kb_src;

#pragma unroll
    for (int mt = 0; mt < 4; ++mt)
#pragma unroll
        for (int nt = 0; nt < 2; ++nt)
            acc[mt][nt] = f32x4{0.f, 0.f, 0.f, 0.f};

    // prologue: stage tile 0 into buf 0 (2 A-rounds + 2 B-rounds of 64 rows)
#pragma unroll
    for (int i = 0; i < 2; ++i) {
        async16(gA + (long)(i * 64) * lda, &lA[0][sOf + i * 64 * BK]);
        async16(gB + (long)(i * 64) * ldb, &lB[0][sOf + i * 64 * BK]);
    }

    for (int kt = 0; kt < kTiles; ++kt) {
        const int cur = kt & 1, nxt = cur ^ 1;
        if (kt + 1 < kTiles) {
            const long k1 = (long)(kt + 1) * BK;
#pragma unroll
            for (int i = 0; i < 2; ++i) {
                async16(gA + k1 + (long)(i * 64) * lda, &lA[nxt][sOf + i * 64 * BK]);
                async16(gB + k1 + (long)(i * 64) * ldb, &lB[nxt][sOf + i * 64 * BK]);
            }
            // 8 outstanding; wait until <=4 -> tile kt's 4 loads complete,
            // tile kt+1's 4 stay in flight across both barriers.
            asm volatile("s_waitcnt vmcnt(4)" ::: "memory");
        } else {
            asm volatile("s_waitcnt vmcnt(0)" ::: "memory");
        }
        BAR_RAW();   // buf[cur] ready on every wave
        const bf16_t* lac = lA[cur];
        const bf16_t* lbc = lB[cur];
#pragma unroll
        for (int h = 0; h < 2; ++h) {
            const bf16_t* pa = lac + (h ? aO1 : aO0);
            const bf16_t* pb = lbc + (h ? bO1 : bO0);
            bf16x8 af[4], bfv[2];
#pragma unroll
            for (int mt = 0; mt < 4; ++mt)
                af[mt] = *(const bf16x8*)(pa + mt * 16 * BK);
#pragma unroll
            for (int nt = 0; nt < 2; ++nt)
                bfv[nt] = *(const bf16x8*)(pb + nt * 16 * BK);
#pragma unroll
            for (int mt = 0; mt < 4; ++mt)
#pragma unroll
                for (int nt = 0; nt < 2; ++nt)
                    acc[mt][nt] = __builtin_amdgcn_mfma_f32_16x16x32_bf16(
                        af[mt], bfv[nt], acc[mt][nt], 0, 0, 0);
        }
        BAR_RAW();   // all waves done reading buf[cur]; safe to overwrite
    }
}

// q/k/v fp32 -> bf16; one float4 per thread (dense coalescing), 8B store
__global__ __launch_bounds__(256) void k_f2b(
    const float* __restrict__ q, const float* __restrict__ k,
    const float* __restrict__ v, bf16_t* __restrict__ Xb)
{
    const int z = blockIdx.z;
    const float* src = (z == 0) ? q : ((z == 1) ? k : v);
    bf16_t* dst = Xb + (long)z * ((long)NB * S_LEN * D_DIM);
    const long i = (long)blockIdx.x * blockDim.x + threadIdx.x;
    float4 a = ((const float4*)src)[i];
    u32 lo = (u32)f2b_bits(a.x) | ((u32)f2b_bits(a.y) << 16);
    u32 hi = (u32)f2b_bits(a.z) | ((u32)f2b_bits(a.w) << 16);
    ((uint2*)(dst))[i] = make_uint2(lo, hi);
}

// W [K=1024,N=1024] fp32 -> Wt [N,K] bf16. 64x64 tiles, vectorized I/O.
__global__ __launch_bounds__(256) void k_tw(
    const float* __restrict__ Wq, const float* __restrict__ Wk,
    const float* __restrict__ Wv, bf16_t* __restrict__ Wt)
{
    __shared__ u32 tile[64][33];
    const int z = blockIdx.z;
    const float* W = (z == 0) ? Wq : ((z == 1) ? Wk : Wv);
    bf16_t* T = Wt + (long)z * D_DIM * D_DIM;
    const int t = threadIdx.x;
    const int k0 = blockIdx.x * 64, n0 = blockIdx.y * 64;
#pragma unroll
    for (int rr = 0; rr < 4; ++rr) {
        const int kr = (t >> 4) + rr * 16;
        const int nq = (t & 15) * 4;
        float4 f = *(const float4*)(W + (long)(k0 + kr) * D_DIM + n0 + nq);
        tile[kr][(nq >> 1)]     = (u32)f2b_bits(f.x) | ((u32)f2b_bits(f.y) << 16);
        tile[kr][(nq >> 1) + 1] = (u32)f2b_bits(f.z) | ((u32)f2b_bits(f.w) << 16);
    }
    __syncthreads();
#pragma unroll
    for (int rr = 0; rr < 2; ++rr) {
        const int nr = (t >> 3) + rr * 32;
        const int j0 = (t & 7) * 4;
        u32x4 o;
#pragma unroll
        for (int jj = 0; jj < 4; ++jj) {
            const int j = j0 + jj;
            const u32 ua = tile[2 * j][nr >> 1];
            const u32 ub = tile[2 * j + 1][nr >> 1];
            const u32 lo = (nr & 1) ? (ua >> 16) : (ua & 0xffffu);
            const u32 hi = (nr & 1) ? (ub >> 16) : (ub & 0xffffu);
            o[jj] = lo | (hi << 16);
        }
        *(u32x4*)(T + (long)(n0 + nr) * D_DIM + k0 + 2 * j0) = o;
    }
}

// WV [S,D] bf16 -> WVt [D,S] bf16 per batch. 64x64 tiles, vectorized I/O.
__global__ __launch_bounds__(256) void k_tv(
    const bf16_t* __restrict__ PrV, bf16_t* __restrict__ WVt)
{
    __shared__ u32 tile[64][33];
    const int b = blockIdx.z;
    const bf16_t* src = PrV + (long)b * S_LEN * D_DIM;
    bf16_t* dst = WVt + (long)b * D_DIM * S_LEN;
    const int t = threadIdx.x;
    const int d0 = blockIdx.x * 64, s0 = blockIdx.y * 64;
#pragma unroll
    for (int rr = 0; rr < 2; ++rr) {
        const int sr = (t >> 3) + rr * 32;
        const int dp0 = (t & 7) * 4;
        u32x4 u = *(const u32x4*)(src + (long)(s0 + sr) * D_DIM + d0 + 2 * dp0);
#pragma unroll
        for (int q = 0; q < 4; ++q) tile[sr][dp0 + q] = u[q];
    }
    __syncthreads();
#pragma unroll
    for (int rr = 0; rr < 2; ++rr) {
        const int dr = (t >> 3) + rr * 32;
        const int j0 = (t & 7) * 4;
        u32x4 o;
#pragma unroll
        for (int jj = 0; jj < 4; ++jj) {
            const int j = j0 + jj;
            const u32 ua = tile[2 * j][dr >> 1];
            const u32 ub = tile[2 * j + 1][dr >> 1];
            const u32 lo = (dr & 1) ? (ua >> 16) : (ua & 0xffffu);
            const u32 hi = (dr & 1) ? (ub >> 16) : (ub & 0xffffu);
            o[jj] = lo | (hi << 16);
        }
        *(u32x4*)(dst + (long)(d0 + dr) * S_LEN + s0 + 2 * j0) = o;
    }
}

// Projections: Pr_z = Xb_z @ Wt_z^T + bias_z, bf16 out (4-wave core).
__global__ __launch_bounds__(256) void k_gemm_proj(
    const bf16_t* __restrict__ Xb, const bf16_t* __restrict__ Wt,
    const float* __restrict__ bq, const float* __restrict__ bk,
    const float* __restrict__ bv, bf16_t* __restrict__ Pr)
{
    const int z = blockIdx.z;
    const bf16_t* A  = Xb + (long)z * ((long)NB * S_LEN * D_DIM);
    const bf16_t* Bt = Wt + (long)z * D_DIM * D_DIM;
    bf16_t* C        = Pr + (long)z * ((long)NB * S_LEN * D_DIM);
    const float* bias = (z == 0) ? bq : ((z == 1) ? bk : bv);
    const int m0 = blockIdx.x * BM, n0 = blockIdx.y * BN;
    f32x4 acc[4][4];
    gemm_bt_core(A, Bt, D_DIM, D_DIM, m0, n0, D_DIM / BK, acc);
    const int lane = threadIdx.x & 63, w = threadIdx.x >> 6;
    const int wr = w >> 1, wc = w & 1;
    const int r0 = m0 + wr * 64 + (lane >> 4) * 4;
    const int c0 = n0 + wc * 64 + (lane & 15);
#pragma unroll
    for (int mt = 0; mt < 4; ++mt)
#pragma unroll
        for (int nt = 0; nt < 4; ++nt) {
            const int col = c0 + nt * 16;
            const float bb = bias[col];
#pragma unroll
            for (int r = 0; r < 4; ++r) {
                const int row = r0 + mt * 16 + r;
                C[(long)row * D_DIM + col] = (bf16_t)(acc[mt][nt][r] + bb);
            }
        }
}

// scores = (WQ @ WK^T) / 32, causal, triangular block enumeration.
// 8-wave dbuf core + XCD-chunked swizzle (136 = 8 x 17: neighbor triangle
// cells share the Q-panel -> same-XCD L2 reuse).
__global__ __launch_bounds__(512) void k_gemm_scores(
    const bf16_t* __restrict__ PrQ, const bf16_t* __restrict__ PrK,
    bf16_t* __restrict__ SC)
{
    const int h = blockIdx.x, b = blockIdx.z;
    const int u = (h & 7) * 17 + (h >> 3);       // bijective: 136 = 8*17
    int ti = (int)((sqrtf(8.0f * (float)u + 1.0f) - 1.0f) * 0.5f);
    while ((ti + 1) * (ti + 2) / 2 <= u) ++ti;
    while (ti * (ti + 1) / 2 > u) --ti;
    const int tj = u - ti * (ti + 1) / 2;
    const bf16_t* A  = PrQ + (long)b * S_LEN * D_DIM;
    const bf16_t* Bt = PrK + (long)b * S_LEN * D_DIM;
    bf16_t* C        = SC  + (long)b * S_LEN * S_LEN;
    const int m0 = ti * BM, n0 = tj * BN;
    f32x4 acc[4][2];
    gemm_bt_dbuf8(A, Bt, D_DIM, D_DIM, m0, n0, D_DIM / BK, acc);
    const int lane = threadIdx.x & 63, w = threadIdx.x >> 6;
    const int wr = w >> 2, wc = w & 3;
    const int r0 = m0 + wr * 64 + (lane >> 4) * 4;
    const int c0 = n0 + wc * 32 + (lane & 15);
#pragma unroll
    for (int mt = 0; mt < 4; ++mt)
#pragma unroll
        for (int nt = 0; nt < 2; ++nt) {
            const int col = c0 + nt * 16;
#pragma unroll
            for (int r = 0; r < 4; ++r) {
                const int row = r0 + mt * 16 + r;
                C[(long)row * S_LEN + col] = (bf16_t)(acc[mt][nt][r] * 0.03125f);
            }
        }
}

// causal softmax, wave-per-row, register-resident, shuffle reductions.
__global__ __launch_bounds__(256) void k_softmax(bf16_t* __restrict__ SC)
{
    const int w = threadIdx.x >> 6, lane = threadIdx.x & 63;
    const int i = blockIdx.x * 4 + w;
    const int b = blockIdx.y;
    bf16_t* row = SC + ((long)b * S_LEN + i) * S_LEN;
    const int n    = i + 1;
    const int jend = ((i >> 7) + 1) << 7;
    const int nch  = (jend + 511) >> 9;
    float x[4][8];
    float mx = -1e30f;
#pragma unroll
    for (int c = 0; c < 4; ++c) {
        if (c < nch) {
            bf16x8 vv = *(const bf16x8*)(row + c * 512 + lane * 8);
#pragma unroll
            for (int e = 0; e < 8; ++e) {
                const int j = c * 512 + lane * 8 + e;
                const float f = (j < n) ? (float)vv[e] : -1e30f;
                x[c][e] = f;
                mx = fmaxf(mx, f);
            }
        }
    }
#pragma unroll
    for (int d = 1; d < 64; d <<= 1) mx = fmaxf(mx, __shfl_xor(mx, d, 64));
    float sm = 0.f;
#pragma unroll
    for (int c = 0; c < 4; ++c) {
        if (c < nch) {
#pragma unroll
            for (int e = 0; e < 8; ++e) {
                const int j = c * 512 + lane * 8 + e;
                float p = (j < n) ? __expf(x[c][e] - mx) : 0.f;
                x[c][e] = p;
                sm += p;
            }
        }
    }
#pragma unroll
    for (int d = 1; d < 64; d <<= 1) sm += __shfl_xor(sm, d, 64);
    const float inv = 1.0f / sm;
#pragma unroll
    for (int c = 0; c < 4; ++c) {
        if (c < nch) {
            bf16x8 o;
#pragma unroll
            for (int e = 0; e < 8; ++e) o[e] = (bf16_t)(x[c][e] * inv);
            *(bf16x8*)(row + c * 512 + lane * 8) = o;
        }
    }
}

// out = P @ WVt^T, fp32 out; K-loop truncated at diagonal tile.
// 8-wave dbuf core + balanced XCD swizzle: XCD i handles ti {15-i, i}
// (equal work 17 units; same-SC-panel blocks co-located; heavy-first).
__global__ __launch_bounds__(512) void k_gemm_pv(
    const bf16_t* __restrict__ SC, const bf16_t* __restrict__ WVt,
    float* __restrict__ Out)
{
    const int h = blockIdx.x, b = blockIdx.z;   // h in 0..127
    const int xcd = h & 7, s = h >> 3;          // s in 0..15
    const int ti  = (s < 8) ? (15 - xcd) : xcd;
    const int n0i = s & 7;
    const bf16_t* A  = SC  + (long)b * S_LEN * S_LEN;
    const bf16_t* Bt = WVt + (long)b * D_DIM * S_LEN;
    float* C         = Out + (long)b * S_LEN * D_DIM;
    const int m0 = ti * BM, n0 = n0i * BN;
    f32x4 acc[4][2];
    gemm_bt_dbuf8(A, Bt, S_LEN, S_LEN, m0, n0, (ti + 1) * (BM / BK), acc);
    const int lane = threadIdx.x & 63, w = threadIdx.x >> 6;
    const int wr = w >> 2, wc = w & 3;
    const int r0 = m0 + wr * 64 + (lane >> 4) * 4;
    const int c0 = n0 + wc * 32 + (lane & 15);
#pragma unroll
    for (int mt = 0; mt < 4; ++mt)
#pragma unroll
        for (int nt = 0; nt < 2; ++nt) {
            const int col = c0 + nt * 16;
#pragma unroll
            for (int r = 0; r < 4; ++r) {
                const int row = r0 + mt * 16 + r;
                C[(long)row * D_DIM + col] = acc[mt][nt][r];
            }
        }
}

extern "C" void kernel_launch(void* const* d_in, const int* in_sizes, int n_in,
                              void* d_out, int out_size, void* d_ws, size_t ws_size,
                              hipStream_t stream)
{
    (void)in_sizes; (void)n_in; (void)out_size; (void)ws_size;
    const float* q  = (const float*)d_in[0];
    const float* k  = (const float*)d_in[1];
    const float* v  = (const float*)d_in[2];
    // d_in[3] = mask: causal triu(1) — applied analytically
    const float* Wq = (const float*)d_in[4];
    const float* bq = (const float*)d_in[5];
    const float* Wk = (const float*)d_in[6];
    const float* bk = (const float*)d_in[7];
    const float* Wv = (const float*)d_in[8];
    const float* bv = (const float*)d_in[9];
    float* out = (float*)d_out;

    // ws layout (bf16 elems): Wt[3*D*D] | Xb[3*B*S*D] (reused as SC[B*S*S]) | Pr[3*B*S*D] | WVt[B*D*S]
    bf16_t* ws = (bf16_t*)d_ws;
    const long nW = (long)D_DIM * D_DIM;           // 1,048,576
    const long nX = (long)NB * S_LEN * D_DIM;      // 8,388,608
    bf16_t* Wt  = ws;
    bf16_t* Xb  = Wt + 3 * nW;
    bf16_t* SC  = Xb;              // aliases Xb: Xb dead after projections
    bf16_t* Pr  = Xb + 3 * nX;
    bf16_t* WVt = Pr + 3 * nX;
    bf16_t* PrQ = Pr;
    bf16_t* PrK = Pr + nX;
    bf16_t* PrV = Pr + 2 * nX;

    k_f2b        <<<dim3(8192, 1, 3),   256, 0, stream>>>(q, k, v, Xb);
    k_tw         <<<dim3(16, 16, 3),    256, 0, stream>>>(Wq, Wk, Wv, Wt);
    k_gemm_proj  <<<dim3(64, 8, 3),     256, 0, stream>>>(Xb, Wt, bq, bk, bv, Pr);
    k_tv         <<<dim3(16, 32, NB),   256, 0, stream>>>(PrV, WVt);
    k_gemm_scores<<<dim3(136, 1, NB),   512, 0, stream>>>(PrQ, PrK, SC);
    k_softmax    <<<dim3(S_LEN / 4, NB),256, 0, stream>>>(SC);
    k_gemm_pv    <<<dim3(128, 1, NB),   512, 0, stream>>>(SC, WVt, out);
}